// Round 3
// baseline (226.352 us; speedup 1.0000x reference)
//
#include <hip/hip_runtime.h>
#include <math.h>

// Problem constants
#define B_   128
#define IN_  1024
#define OUT_ 1024
#define E_   32

// moe_main tiling
#define CHUNK 16             // samples per block
#define OSEG  128            // output cols per block (32 per wave, 8 per lane)
#define NOSEG (OUT_ / OSEG)  // 8
#define MAXCH (B_ / CHUNK)   // 8

// ---------------- Kernel A: routing (both routers) + top-2 softmax + bias init ----
// route layout per sample b (8 floats): [i0, i1, p0, p1, ib0, ib1, pb0, pb1]
__global__ __launch_bounds__(256) void route_fused(
    const float* __restrict__ x, const float* __restrict__ rw,
    const float* __restrict__ brw, const float* __restrict__ eb,
    float* __restrict__ route, float* __restrict__ out) {
  int b = blockIdx.x;
  int t = threadIdx.x;
  __shared__ float xs[IN_];
  __shared__ float4 part4[16][16];   // [i-chunk][group]
  __shared__ float lg[64];           // 0..31 router0 logits, 32..63 router1
  __shared__ float res[8];

  ((float4*)xs)[t] = ((const float4*)(x + (size_t)b * IN_))[t];
  __syncthreads();

  // thread = (grp, q): grp 0..7 -> rw e-cols [4g,4g+4); grp 8..15 -> brw;
  // q 0..15 -> i-chunk of 64. float4 weight loads, 8 in flight.
  int grp = t & 15;
  int q   = t >> 4;
  const float* wsel = (grp < 8) ? rw : brw;
  const float* wp = wsel + (grp & 7) * 4;
  float4 acc = make_float4(0.f, 0.f, 0.f, 0.f);
  int ibeg = q * 64;
  #pragma unroll 8
  for (int i = ibeg; i < ibeg + 64; ++i) {
    float xv = xs[i];
    float4 w4 = *(const float4*)(wp + (size_t)i * E_);
    acc.x += xv * w4.x; acc.y += xv * w4.y;
    acc.z += xv * w4.z; acc.w += xv * w4.w;
  }
  part4[q][grp] = acc;
  __syncthreads();

  if (t < 16) {
    float4 L = make_float4(0.f, 0.f, 0.f, 0.f);
    #pragma unroll
    for (int qq = 0; qq < 16; ++qq) {
      float4 p = part4[qq][t];
      L.x += p.x; L.y += p.y; L.z += p.z; L.w += p.w;
    }
    ((float4*)lg)[t] = L;
  }
  __syncthreads();

  if (t < 2) {
    const float* l = lg + t * 32;
    int bi0 = -1, bi1 = -1;
    float v0 = -INFINITY, v1 = -INFINITY;
    for (int ee = 0; ee < E_; ++ee) {
      float v = l[ee];
      if (v > v0) { v1 = v0; bi1 = bi0; v0 = v; bi0 = ee; }
      else if (v > v1) { v1 = v; bi1 = ee; }
    }
    float p0 = 1.f / (1.f + expf(v1 - v0));
    float p1 = 1.f - p0;
    float* r = route + (size_t)b * 8 + t * 4;
    r[0] = __int_as_float(bi0);
    r[1] = __int_as_float(bi1);
    r[2] = p0;
    r[3] = p1;
    res[t * 4 + 0] = __int_as_float(bi0);
    res[t * 4 + 1] = __int_as_float(bi1);
    res[t * 4 + 2] = p0;
    res[t * 4 + 3] = p1;
  }
  __syncthreads();

  // bias init: out[b] = pb0*eb[ib0] + pb1*eb[ib1]
  int ib0 = __float_as_int(res[4]);
  int ib1 = __float_as_int(res[5]);
  float pb0 = res[6], pb1 = res[7];
  float4 b0 = ((const float4*)(eb + (size_t)ib0 * OUT_))[t];
  float4 b1 = ((const float4*)(eb + (size_t)ib1 * OUT_))[t];
  float4 o;
  o.x = pb0 * b0.x + pb1 * b1.x;
  o.y = pb0 * b0.y + pb1 * b1.y;
  o.z = pb0 * b0.z + pb1 * b1.z;
  o.w = pb0 * b0.w + pb1 * b1.w;
  ((float4*)(out + (size_t)b * OUT_))[t] = o;
}

// ---------------- Kernel A2: per-expert sample lists (LDS-staged, deterministic) ----
__global__ __launch_bounds__(128) void build_lists(
    const float* __restrict__ route, int* __restrict__ counts,
    int* __restrict__ list_b, float* __restrict__ list_p) {
  __shared__ float4 r_sh[B_];
  int t = threadIdx.x;  // 128
  r_sh[t] = *(const float4*)(route + (size_t)t * 8);  // [i0,i1,p0,p1]
  __syncthreads();
  if (t < E_) {
    int c = 0;
    for (int b = 0; b < B_; ++b) {
      float4 r = r_sh[b];
      int i0 = __float_as_int(r.x);
      int i1 = __float_as_int(r.y);
      if (i0 == t)      { list_b[t * B_ + c] = b; list_p[t * B_ + c] = r.z; ++c; }
      else if (i1 == t) { list_b[t * B_ + c] = b; list_p[t * B_ + c] = r.w; ++c; }
    }
    counts[t] = c;
  }
}

// ---------------- Kernel B: grouped expert matvecs ----------------
// block = (e, oseg, chunk); 256 threads = 4 waves.
// lane = (sample sl = lane>>2, colgroup cg = lane&3); wave w owns cols
// [oseg*128 + w*32 + cg*8, +8). No LDS, no barriers; weight reads disjoint
// across waves; x / weight same-address lane dups merge in the coalescer.
// One atomicAdd per output element.
__global__ __launch_bounds__(256) void moe_main(
    const float* __restrict__ x, const float* __restrict__ ew,
    const int* __restrict__ counts, const int* __restrict__ list_b,
    const float* __restrict__ list_p, float* __restrict__ out) {
  int e    = blockIdx.x;
  int oseg = blockIdx.y;
  int ch   = blockIdx.z;
  int c = counts[e];
  int s0 = ch * CHUNK;
  if (s0 >= c) return;
  int ns = min(CHUNK, c - s0);

  int t    = threadIdx.x;
  int w    = t >> 6;
  int lane = t & 63;
  int sl   = lane >> 2;    // 0..15
  int cg   = lane & 3;     // 0..3
  int col  = oseg * OSEG + w * 32 + cg * 8;

  int sidx = s0 + min(sl, ns - 1);
  int bsmp = list_b[e * B_ + sidx];
  float p  = (sl < ns) ? list_p[e * B_ + sidx] : 0.f;

  const float* xrow = x + (size_t)bsmp * IN_;
  const float* wb   = ew + (size_t)e * IN_ * OUT_ + col;

  float4 a0 = make_float4(0.f, 0.f, 0.f, 0.f);
  float4 a1 = make_float4(0.f, 0.f, 0.f, 0.f);

  #pragma unroll 2
  for (int i0 = 0; i0 < IN_; i0 += 4) {
    float4 xv = *(const float4*)(xrow + i0);
    #pragma unroll
    for (int k = 0; k < 4; ++k) {
      float f = (k == 0) ? xv.x : (k == 1) ? xv.y : (k == 2) ? xv.z : xv.w;
      const float* wr = wb + (size_t)(i0 + k) * OUT_;
      float4 w0 = *(const float4*)(wr);
      float4 w1 = *(const float4*)(wr + 4);
      a0.x += f * w0.x; a0.y += f * w0.y; a0.z += f * w0.z; a0.w += f * w0.w;
      a1.x += f * w1.x; a1.y += f * w1.y; a1.z += f * w1.z; a1.w += f * w1.w;
    }
  }

  if (sl < ns) {
    float* op = out + (size_t)bsmp * OUT_ + col;
    atomicAdd(op + 0, p * a0.x);
    atomicAdd(op + 1, p * a0.y);
    atomicAdd(op + 2, p * a0.z);
    atomicAdd(op + 3, p * a0.w);
    atomicAdd(op + 4, p * a1.x);
    atomicAdd(op + 5, p * a1.y);
    atomicAdd(op + 6, p * a1.z);
    atomicAdd(op + 7, p * a1.w);
  }
}

extern "C" void kernel_launch(void* const* d_in, const int* in_sizes, int n_in,
                              void* d_out, int out_size, void* d_ws, size_t ws_size,
                              hipStream_t stream) {
  const float* x   = (const float*)d_in[0];
  const float* rw  = (const float*)d_in[1];
  const float* brw = (const float*)d_in[2];
  const float* ew  = (const float*)d_in[3];
  const float* eb  = (const float*)d_in[4];
  float* out = (float*)d_out;

  float* route  = (float*)d_ws;                                   // 128*8 floats = 4 KB
  int*   counts = (int*)((char*)d_ws + 4096);                     // 32 ints
  int*   list_b = (int*)((char*)d_ws + 4096 + 128);               // 32*128 ints
  float* list_p = (float*)((char*)d_ws + 4096 + 128 + 16384);     // 32*128 floats

  route_fused<<<B_, 256, 0, stream>>>(x, rw, brw, eb, route, out);
  build_lists<<<1, 128, 0, stream>>>(route, counts, list_b, list_p);
  moe_main<<<dim3(E_, NOSEG, MAXCH), 256, 0, stream>>>(x, ew, counts, list_b, list_p, out);
}

// Round 4
// 117.321 us; speedup vs baseline: 1.9293x; 1.9293x over previous
//
#include <hip/hip_runtime.h>
#include <math.h>

// Problem constants
#define B_   128
#define IN_  1024
#define OUT_ 1024
#define E_   32

// moe_main tiling
#define ISEG  128
#define NISEG (IN_ / ISEG)    // 8
#define OSEG  128
#define NOSEG (OUT_ / OSEG)   // 8
#define SG    8               // samples per group (one per 32-thread slot)

// ---------------- Kernel A: routing, one block per (sample, router) --------------
// route layout: route[(b*2 + r)*4] = [idx0, idx1, p0, p1]  (idx bit-cast)
__global__ __launch_bounds__(256) void route_kernel(
    const float* __restrict__ x, const float* __restrict__ rw,
    const float* __restrict__ brw, float* __restrict__ route) {
  int b = blockIdx.x;
  int r = blockIdx.y;
  int t = threadIdx.x;
  const float* w = r ? brw : rw;

  __shared__ float xs[IN_];
  __shared__ float part[8][E_];
  __shared__ float lg[E_];

  ((float4*)xs)[t] = ((const float4*)(x + (size_t)b * IN_))[t];
  __syncthreads();

  // thread t: e = t&31, i-chunk = t>>5 (128 wide). Lane-contiguous w reads.
  int e  = t & 31;
  int ic = t >> 5;
  int base = ic * ISEG;
  float acc = 0.f;
  #pragma unroll 8
  for (int i = 0; i < ISEG; ++i)
    acc += xs[base + i] * w[(size_t)(base + i) * E_ + e];
  part[ic][e] = acc;
  __syncthreads();

  if (t < E_) {
    float s = 0.f;
    #pragma unroll
    for (int q = 0; q < 8; ++q) s += part[q][t];
    lg[t] = s;
  }
  __syncthreads();

  if (t == 0) {
    int bi0 = -1, bi1 = -1;
    float v0 = -INFINITY, v1 = -INFINITY;
    for (int ee = 0; ee < E_; ++ee) {
      float v = lg[ee];
      if (v > v0) { v1 = v0; bi1 = bi0; v0 = v; bi0 = ee; }
      else if (v > v1) { v1 = v; bi1 = ee; }
    }
    float p0 = 1.f / (1.f + expf(v1 - v0));
    float* rp = route + ((size_t)b * 2 + r) * 4;
    rp[0] = __int_as_float(bi0);
    rp[1] = __int_as_float(bi1);
    rp[2] = p0;
    rp[3] = 1.f - p0;
  }
}

// ---------------- Kernel A2: per-expert sample lists (deterministic scan) --------
__global__ __launch_bounds__(128) void build_lists(
    const float* __restrict__ route, int* __restrict__ counts,
    int* __restrict__ list_b, float* __restrict__ list_p) {
  __shared__ float4 r_sh[B_];
  int t = threadIdx.x;  // 128
  r_sh[t] = *(const float4*)(route + (size_t)t * 8);  // router-0 entry of sample t
  __syncthreads();
  if (t < E_) {
    int c = 0;
    for (int b = 0; b < B_; ++b) {
      float4 r = r_sh[b];
      int i0 = __float_as_int(r.x);
      int i1 = __float_as_int(r.y);
      if (i0 == t)      { list_b[t * B_ + c] = b; list_p[t * B_ + c] = r.z; ++c; }
      else if (i1 == t) { list_b[t * B_ + c] = b; list_p[t * B_ + c] = r.w; ++c; }
    }
    counts[t] = c;
  }
}

// ---------------- Kernel B: bias init: out[b] = pb0*eb[ib0] + pb1*eb[ib1] --------
__global__ __launch_bounds__(256) void bias_init(
    const float* __restrict__ route, const float* __restrict__ eb,
    float* __restrict__ out) {
  int b = blockIdx.x;
  int t = threadIdx.x;
  const float* rp = route + ((size_t)b * 2 + 1) * 4;
  int ib0 = __float_as_int(rp[0]);
  int ib1 = __float_as_int(rp[1]);
  float pb0 = rp[2], pb1 = rp[3];
  float4 b0 = ((const float4*)(eb + (size_t)ib0 * OUT_))[t];
  float4 b1 = ((const float4*)(eb + (size_t)ib1 * OUT_))[t];
  float4 o;
  o.x = pb0 * b0.x + pb1 * b1.x;
  o.y = pb0 * b0.y + pb1 * b1.y;
  o.z = pb0 * b0.z + pb1 * b1.z;
  o.w = pb0 * b0.w + pb1 * b1.w;
  ((float4*)(out + (size_t)b * OUT_))[t] = o;
}

// ---------------- Kernel C: grouped expert matvecs, (e, iseg, oseg) blocks -------
// 256 threads: c32 = t&31 -> float4 of cols, sg = t>>5 -> sample slot (8/group).
// acc is one static float4; weight reads 512B-contiguous per instruction
// (sg-duplicates broadcast); x tile staged in LDS. One atomicAdd per
// (sample, col, iseg) contribution: 8 per output element total.
__global__ __launch_bounds__(256) void moe_main(
    const float* __restrict__ x, const float* __restrict__ ew,
    const int* __restrict__ counts, const int* __restrict__ list_b,
    const float* __restrict__ list_p, float* __restrict__ out) {
  int e    = blockIdx.x;
  int iseg = blockIdx.y;
  int oseg = blockIdx.z;
  int c = counts[e];
  if (c == 0) return;

  int t   = threadIdx.x;
  int c32 = t & 31;
  int sg  = t >> 5;
  int col = oseg * OSEG + c32 * 4;

  const float* wb = ew + ((size_t)e * IN_ + (size_t)iseg * ISEG) * OUT_ + col;

  __shared__ float xs[SG][ISEG];
  __shared__ int   bs[SG];
  __shared__ float ps[SG];

  for (int g0 = 0; g0 < c; g0 += SG) {
    __syncthreads();   // protect xs/bs from previous iteration's readers
    if (t < SG) {
      int idx = g0 + t;
      int cidx = min(idx, c - 1);
      bs[t] = list_b[e * B_ + cidx];
      ps[t] = (idx < c) ? list_p[e * B_ + cidx] : 0.f;
    }
    __syncthreads();

    // stage x tile: thread t loads float4 (row sg, chunk c32)
    ((float4*)xs[sg])[c32] =
        ((const float4*)(x + (size_t)bs[sg] * IN_ + iseg * ISEG))[c32];
    __syncthreads();

    float4 a = make_float4(0.f, 0.f, 0.f, 0.f);
    const float* xr = xs[sg];
    #pragma unroll 8
    for (int i = 0; i < ISEG; ++i) {
      float f = xr[i];
      float4 w4 = *(const float4*)(wb + (size_t)i * OUT_);
      a.x += f * w4.x; a.y += f * w4.y;
      a.z += f * w4.z; a.w += f * w4.w;
    }

    if (g0 + sg < c) {
      float p = ps[sg];
      float* op = out + (size_t)bs[sg] * OUT_ + col;
      atomicAdd(op + 0, p * a.x);
      atomicAdd(op + 1, p * a.y);
      atomicAdd(op + 2, p * a.z);
      atomicAdd(op + 3, p * a.w);
    }
  }
}

extern "C" void kernel_launch(void* const* d_in, const int* in_sizes, int n_in,
                              void* d_out, int out_size, void* d_ws, size_t ws_size,
                              hipStream_t stream) {
  const float* x   = (const float*)d_in[0];
  const float* rw  = (const float*)d_in[1];
  const float* brw = (const float*)d_in[2];
  const float* ew  = (const float*)d_in[3];
  const float* eb  = (const float*)d_in[4];
  float* out = (float*)d_out;

  float* route  = (float*)d_ws;                                   // 128*2*4 floats = 4 KB
  int*   counts = (int*)((char*)d_ws + 4096);                     // 32 ints
  int*   list_b = (int*)((char*)d_ws + 4096 + 128);               // 32*128 ints
  float* list_p = (float*)((char*)d_ws + 4096 + 128 + 16384);     // 32*128 floats

  route_kernel<<<dim3(B_, 2), 256, 0, stream>>>(x, rw, brw, route);
  build_lists<<<1, 128, 0, stream>>>(route, counts, list_b, list_p);
  bias_init<<<B_, 256, 0, stream>>>(route, eb, out);
  moe_main<<<dim3(E_, NISEG, NOSEG), 256, 0, stream>>>(x, ew, counts, list_b, list_p, out);
}

// Round 5
// 112.092 us; speedup vs baseline: 2.0193x; 1.0467x over previous
//
#include <hip/hip_runtime.h>
#include <math.h>

// Problem constants
#define B_   128
#define IN_  1024
#define OUT_ 1024
#define E_   32

// moe_main tiling
#define S_    16              // samples per group
#define OSEG  128             // output cols per block
#define NOSEG (OUT_ / OSEG)   // 8
#define IH    2               // i halves
#define IHLEN (IN_ / IH)      // 512
#define XPAD  20              // padded stride of transposed x tile (floats)

// ---------------- Kernel A: routing, one block per (sample, router) --------------
// route layout: route[(b*2 + r)*4] = [idx0, idx1, p0, p1]  (idx bit-cast)
__global__ __launch_bounds__(256) void route_kernel(
    const float* __restrict__ x, const float* __restrict__ rw,
    const float* __restrict__ brw, float* __restrict__ route) {
  int b = blockIdx.x;
  int r = blockIdx.y;
  int t = threadIdx.x;
  const float* w = r ? brw : rw;

  __shared__ float xs[IN_];
  __shared__ float part[8][E_];
  __shared__ float lg[E_];

  ((float4*)xs)[t] = ((const float4*)(x + (size_t)b * IN_))[t];
  __syncthreads();

  int e  = t & 31;
  int ic = t >> 5;
  int base = ic * 128;
  float acc = 0.f;
  #pragma unroll 8
  for (int i = 0; i < 128; ++i)
    acc += xs[base + i] * w[(size_t)(base + i) * E_ + e];
  part[ic][e] = acc;
  __syncthreads();

  if (t < E_) {
    float s = 0.f;
    #pragma unroll
    for (int q = 0; q < 8; ++q) s += part[q][t];
    lg[t] = s;
  }
  __syncthreads();

  if (t == 0) {
    int bi0 = -1, bi1 = -1;
    float v0 = -INFINITY, v1 = -INFINITY;
    for (int ee = 0; ee < E_; ++ee) {
      float v = lg[ee];
      if (v > v0) { v1 = v0; bi1 = bi0; v0 = v; bi0 = ee; }
      else if (v > v1) { v1 = v; bi1 = ee; }
    }
    float p0 = 1.f / (1.f + expf(v1 - v0));
    float* rp = route + ((size_t)b * 2 + r) * 4;
    rp[0] = __int_as_float(bi0);
    rp[1] = __int_as_float(bi1);
    rp[2] = p0;
    rp[3] = 1.f - p0;
  }
}

// ---------------- Kernel A2: per-expert sample lists (deterministic scan) --------
__global__ __launch_bounds__(128) void build_lists(
    const float* __restrict__ route, int* __restrict__ counts,
    int* __restrict__ list_b, float* __restrict__ list_p) {
  __shared__ float4 r_sh[B_];
  int t = threadIdx.x;  // 128
  r_sh[t] = *(const float4*)(route + (size_t)t * 8);  // router-0 entry of sample t
  __syncthreads();
  if (t < E_) {
    int c = 0;
    for (int b = 0; b < B_; ++b) {
      float4 r = r_sh[b];
      int i0 = __float_as_int(r.x);
      int i1 = __float_as_int(r.y);
      if (i0 == t)      { list_b[t * B_ + c] = b; list_p[t * B_ + c] = r.z; ++c; }
      else if (i1 == t) { list_b[t * B_ + c] = b; list_p[t * B_ + c] = r.w; ++c; }
    }
    counts[t] = c;
  }
}

// ---------------- Kernel B: bias init: out[b] = pb0*eb[ib0] + pb1*eb[ib1] --------
__global__ __launch_bounds__(256) void bias_init(
    const float* __restrict__ route, const float* __restrict__ eb,
    float* __restrict__ out) {
  int b = blockIdx.x;
  int t = threadIdx.x;
  const float* rp = route + ((size_t)b * 2 + 1) * 4;
  int ib0 = __float_as_int(rp[0]);
  int ib1 = __float_as_int(rp[1]);
  float pb0 = rp[2], pb1 = rp[3];
  float4 b0 = ((const float4*)(eb + (size_t)ib0 * OUT_))[t];
  float4 b1 = ((const float4*)(eb + (size_t)ib1 * OUT_))[t];
  float4 o;
  o.x = pb0 * b0.x + pb1 * b1.x;
  o.y = pb0 * b0.y + pb1 * b1.y;
  o.z = pb0 * b0.z + pb1 * b1.z;
  o.w = pb0 * b0.w + pb1 * b1.w;
  ((float4*)(out + (size_t)b * OUT_))[t] = o;
}

// ---------------- Kernel C: grouped expert matvecs ----------------
// block = (e, oseg, ih); 512 threads = 8 waves. Group of up to 16 samples shares
// one pass over the weight sub-tile (512 i x 128 cols, read exactly once).
// Wave w owns i-octant [w*64,+64); lane half h owns 32 of those; c32 = lane&31
// owns 4 cols. Each weight float4 feeds 16 samples (64 FMAs). x is staged
// transposed xs[i][s] (stride 20: b128-aligned, broadcast reads).
__global__ __launch_bounds__(512) void moe_main(
    const float* __restrict__ x, const float* __restrict__ ew,
    const int* __restrict__ counts, const int* __restrict__ list_b,
    const float* __restrict__ list_p, float* __restrict__ out) {
  int e    = blockIdx.x;
  int oseg = blockIdx.y;
  int ih   = blockIdx.z;
  int c = counts[e];
  if (c == 0) return;

  __shared__ float xs[IHLEN][XPAD];
  __shared__ int   bs[S_];
  __shared__ float ps[S_];

  int t    = threadIdx.x;
  int w    = t >> 6;
  int lane = t & 63;
  int h    = lane >> 5;
  int c32  = lane & 31;
  int col  = oseg * OSEG + c32 * 4;

  for (int g0 = 0; g0 < c; g0 += S_) {
    __syncthreads();   // previous iteration's readers done
    if (t < S_) {
      int idx = g0 + t;
      int cidx = min(idx, c - 1);
      bs[t] = list_b[e * B_ + cidx];
      ps[t] = (idx < c) ? list_p[e * B_ + cidx] : 0.f;
    }
    __syncthreads();

    // stage x transposed: thread (s = t&15, ic = t>>4) covers 16 i's
    {
      int s  = t & 15;
      int ic = t >> 4;            // 0..31
      const float* xr = x + (size_t)bs[s] * IN_ + ih * IHLEN + ic * 16;
      #pragma unroll
      for (int k = 0; k < 4; ++k) {
        float4 v = *(const float4*)(xr + k * 4);
        int i0 = ic * 16 + k * 4;
        xs[i0 + 0][s] = v.x;
        xs[i0 + 1][s] = v.y;
        xs[i0 + 2][s] = v.z;
        xs[i0 + 3][s] = v.w;
      }
    }
    __syncthreads();

    float4 acc[S_];
    #pragma unroll
    for (int s = 0; s < S_; ++s) acc[s] = make_float4(0.f, 0.f, 0.f, 0.f);

    // i range for this lane: [w*64 + h*32, +32) within the block's 512
    int ibase = w * 64 + h * 32;
    const float* wp = ew + ((size_t)e * IN_ + (size_t)(ih * IHLEN + ibase)) * OUT_ + col;

    #pragma unroll 2
    for (int ii = 0; ii < 32; ++ii) {
      float4 w4 = *(const float4*)(wp + (size_t)ii * OUT_);
      const float* xrow = xs[ibase + ii];
      float4 xv0 = ((const float4*)xrow)[0];
      float4 xv1 = ((const float4*)xrow)[1];
      float4 xv2 = ((const float4*)xrow)[2];
      float4 xv3 = ((const float4*)xrow)[3];
      const float xf[16] = {xv0.x, xv0.y, xv0.z, xv0.w,
                            xv1.x, xv1.y, xv1.z, xv1.w,
                            xv2.x, xv2.y, xv2.z, xv2.w,
                            xv3.x, xv3.y, xv3.z, xv3.w};
      #pragma unroll
      for (int s = 0; s < S_; ++s) {
        float f = xf[s];
        acc[s].x += f * w4.x;
        acc[s].y += f * w4.y;
        acc[s].z += f * w4.z;
        acc[s].w += f * w4.w;
      }
    }

    // merge the two i-halves within the wave (lane ^ 32 has same (s, cols))
    #pragma unroll
    for (int s = 0; s < S_; ++s) {
      acc[s].x += __shfl_xor(acc[s].x, 32);
      acc[s].y += __shfl_xor(acc[s].y, 32);
      acc[s].z += __shfl_xor(acc[s].z, 32);
      acc[s].w += __shfl_xor(acc[s].w, 32);
    }

    if (h == 0) {
      #pragma unroll
      for (int s = 0; s < S_; ++s) {
        if (g0 + s < c) {
          float p = ps[s];
          float* op = out + (size_t)bs[s] * OUT_ + col;
          atomicAdd(op + 0, p * acc[s].x);
          atomicAdd(op + 1, p * acc[s].y);
          atomicAdd(op + 2, p * acc[s].z);
          atomicAdd(op + 3, p * acc[s].w);
        }
      }
    }
  }
}

extern "C" void kernel_launch(void* const* d_in, const int* in_sizes, int n_in,
                              void* d_out, int out_size, void* d_ws, size_t ws_size,
                              hipStream_t stream) {
  const float* x   = (const float*)d_in[0];
  const float* rw  = (const float*)d_in[1];
  const float* brw = (const float*)d_in[2];
  const float* ew  = (const float*)d_in[3];
  const float* eb  = (const float*)d_in[4];
  float* out = (float*)d_out;

  float* route  = (float*)d_ws;                                   // 128*2*4 floats = 4 KB
  int*   counts = (int*)((char*)d_ws + 4096);                     // 32 ints
  int*   list_b = (int*)((char*)d_ws + 4096 + 128);               // 32*128 ints
  float* list_p = (float*)((char*)d_ws + 4096 + 128 + 16384);     // 32*128 floats

  route_kernel<<<dim3(B_, 2), 256, 0, stream>>>(x, rw, brw, route);
  build_lists<<<1, 128, 0, stream>>>(route, counts, list_b, list_p);
  bias_init<<<B_, 256, 0, stream>>>(route, eb, out);
  moe_main<<<dim3(E_, NOSEG, IH), 512, 0, stream>>>(x, ew, counts, list_b, list_p, out);
}